// Round 8
// baseline (202.676 us; speedup 1.0000x reference)
//
#include <hip/hip_runtime.h>

#define BB 4
#define CC 256
#define NN 4096

typedef __attribute__((ext_vector_type(8))) short bh8;
typedef __attribute__((ext_vector_type(4))) float f32x4;
typedef __attribute__((ext_vector_type(16))) float f32x16;

// workspace layout (bytes)
#define WPK_OFF  0                        // 20*8*64*8 bf16 = 163840 (B-frag packed W)
#define BALL_OFF 163840                   // 320 f32
#define QBF_OFF  165888                   // B*N*32 bf16 = 1 MB
#define KBF_OFF  (165888 + 1048576)
#define VBF_OFF  (165888 + 2097152)       // B*C*N bf16 = 8 MB

typedef const __attribute__((address_space(1))) void* gas_t;
typedef __attribute__((address_space(3))) void* las_t;
__device__ inline void gld16(const void* g, void* l) {
    __builtin_amdgcn_global_load_lds((gas_t)g, (las_t)l, 16, 0, 0);
}

__device__ inline int pack2bf(float a, float b) {
    unsigned ua = __builtin_bit_cast(unsigned, a) + 0x8000u;
    unsigned ub = __builtin_bit_cast(unsigned, b) + 0x8000u;
    return (int)__builtin_amdgcn_perm(ub, ua, 0x07060302u);
}
__device__ inline short f2bf1(float a) {
    return (short)((__builtin_bit_cast(unsigned, a) + 0x8000u) >> 16);
}

// ---------------- prep: Wpk B-fragments + ball
__global__ __launch_bounds__(256) void prep_w(const float* __restrict__ Wq,
        const float* __restrict__ bq, const float* __restrict__ Wk,
        const float* __restrict__ bk, const float* __restrict__ Wv,
        const float* __restrict__ bv, short* __restrict__ Wpk,
        float* __restrict__ ball) {
    int tid = blockIdx.x * 256 + threadIdx.x;
    if (tid < 10240) {
        int lane = tid & 63;
        int fc = tid >> 6;                 // mt*8 + ck
        int mt = fc >> 3, ck = fc & 7;
        int m = mt * 16 + (lane & 15);
        int c0 = ck * 32 + (lane >> 4) * 8;
        const float* wrow;
        if (m < 32)      wrow = Wq + m * 256;
        else if (m < 64) wrow = Wk + (m - 32) * 256;
        else             wrow = Wv + (m - 64) * 256;
        int d[4];
        #pragma unroll
        for (int p = 0; p < 4; ++p)
            d[p] = pack2bf(wrow[c0 + 2 * p], wrow[c0 + 2 * p + 1]);
        *(int4*)(Wpk + tid * 8) = make_int4(d[0], d[1], d[2], d[3]);
    }
    if (tid < 320) {
        float b2 = tid < 32 ? bq[tid] : (tid < 64 ? bk[tid - 32] : bv[tid - 64]);
        ball[tid] = b2;
    }
}

// ---------------- projections as MFMA GEMM, x staged coalesced via LDS
// block = 32-n slab x all 320 m; 4 waves = (n-sub 0/1) x (m-half 0/1). grid 512.
__global__ __launch_bounds__(256) void proj(const float* __restrict__ x,
        const short* __restrict__ Wpk, const float* __restrict__ ball,
        short* __restrict__ qbf, short* __restrict__ kbf,
        short* __restrict__ vbf) {
    __shared__ float xs[8192];             // 32 KB: x[256c][32n] fp32, granule-linear
    int t = threadIdx.x;
    int w = t >> 6, lane = t & 63, quad = lane >> 4, c15 = lane & 15;
    int b = blockIdx.x >> 7;
    int n0 = (blockIdx.x & 127) * 32;
    const float* xb = x + (size_t)b * CC * NN + n0;

    // stage: wave w covers c rows [w*64, w*64+64), 8 gld16 (coalesced 128 B rows)
    #pragma unroll
    for (int r = 0; r < 8; ++r) {
        const float* src = xb + (size_t)(w * 64 + r * 8 + (lane >> 3)) * NN + (lane & 7) * 4;
        gld16(src, (char*)xs + w * 8192 + r * 1024);
    }
    __syncthreads();

    int ns = w & 1, mh = w >> 1;           // n-sub, m-half
    int nb = ns * 16;

    // A-frags from LDS: m = c15 (row n0+nb+c15), k = quad*8+e
    bh8 af[8];
    #pragma unroll
    for (int ck = 0; ck < 8; ++ck) {
        float v[8];
        #pragma unroll
        for (int e = 0; e < 8; ++e)
            v[e] = xs[(ck * 32 + quad * 8 + e) * 32 + nb + c15];
        int d[4];
        #pragma unroll
        for (int p = 0; p < 4; ++p) d[p] = pack2bf(v[2 * p], v[2 * p + 1]);
        af[ck] = __builtin_bit_cast(bh8, make_int4(d[0], d[1], d[2], d[3]));
    }

    // this wave's 10 m-tiles (half of 20), in pairs for MFMA ILP
    #pragma unroll
    for (int mpi = 0; mpi < 5; ++mpi) {
        int mtA = mh * 10 + mpi * 2, mtB = mtA + 1;
        float blA = ball[mtA * 16 + c15], blB = ball[mtB * 16 + c15];
        f32x4 accA = {blA, blA, blA, blA}, accB = {blB, blB, blB, blB};
        #pragma unroll
        for (int ck = 0; ck < 8; ++ck) {
            bh8 wfA = *(const bh8*)(Wpk + ((mtA * 8 + ck) * 64 + lane) * 8);
            bh8 wfB = *(const bh8*)(Wpk + ((mtB * 8 + ck) * 64 + lane) * 8);
            accA = __builtin_amdgcn_mfma_f32_16x16x32_bf16(af[ck], wfA, accA, 0, 0, 0);
            accB = __builtin_amdgcn_mfma_f32_16x16x32_bf16(af[ck], wfB, accB, 0, 0, 0);
        }
        #pragma unroll
        for (int half = 0; half < 2; ++half) {
            int mt = mtA + half;
            f32x4 acc = half ? accB : accA;
            if (mt < 4) {
                short* dst = (mt < 2) ? qbf : kbf;
                int m = (mt & 1) * 16 + c15;
                #pragma unroll
                for (int r = 0; r < 4; ++r)
                    dst[(size_t)(b * NN + n0 + nb + quad * 4 + r) * 32 + m] = f2bf1(acc[r]);
            } else {
                int c = mt * 16 + c15 - 64;
                int2 pk;
                pk.x = pack2bf(acc[0], acc[1]);
                pk.y = pack2bf(acc[2], acc[3]);
                *(int2*)(vbf + (size_t)b * CC * NN + (size_t)c * NN + n0 + nb + quad * 4) = pk;
            }
        }
    }
}

// ---------------- fused flash attention v3: V direct from L2, LDS = P only
// block = 4 waves, 256c x 64i x all-j. wave = 64c x 64i via 4x mfma_32x32x16.
// QK: jsub = w (16 j/step/wave, all 64 i). Single barrier/step (P dbuf).
__global__ __launch_bounds__(256) void flash_attn(
        const short* __restrict__ qbf, const short* __restrict__ kbf,
        const short* __restrict__ vbf, const float* __restrict__ x,
        const float* __restrict__ gamma, float* __restrict__ out) {
    __shared__ char lds[17408];            // P 2x8KB @0 | lred 1KB @16384

    int bid = blockIdx.x;
    int b = bid & 3, i0 = (bid >> 2) * 64; // batch -> XCD pair (V/K L2-resident)
    int t = threadIdx.x;
    int w = t >> 6, lane = t & 63, quad = lane >> 4, c15 = lane & 15;
    int l31 = lane & 31, l5 = lane >> 5;

    const short* qb = qbf + (size_t)b * NN * 32;
    const short* kb = kbf + (size_t)b * NN * 32;
    const short* vb = vbf + (size_t)b * CC * NN;

    // Q fragments (16x16 B-operand), isub = 0..3
    bh8 qf[4];
    #pragma unroll
    for (int is4 = 0; is4 < 4; ++is4)
        qf[is4] = *(const bh8*)(qb + (size_t)(i0 + is4 * 16 + c15) * 32 + quad * 8);

    // K pointer (16x16 A-operand): j-row = w*16 + c15 (+ jt*64)
    const short* kptr = kb + (size_t)(w * 16 + c15) * 32 + quad * 8;

    // V pointers (32x32 A-operand): m = c-row = base + l31, k = j = l5*8 + e
    const short* vr0 = vb + (size_t)(w * 64 + l31) * NN + l5 * 8;
    const short* vr1 = vr0 + (size_t)32 * NN;

    f32x16 acc[2][2];                      // [c-sub][i-sub], 64 VGPRs
    #pragma unroll
    for (int cs = 0; cs < 2; ++cs)
        #pragma unroll
        for (int is = 0; is < 2; ++is)
            #pragma unroll
            for (int r = 0; r < 16; ++r) acc[cs][is][r] = 0.0f;
    float lsum[4] = {0.f, 0.f, 0.f, 0.f};
    const f32x4 initc = {-12.f, -12.f, -12.f, -12.f};  // softmax shift folded into C

    // prologue: V regs for step 0, K frag for step 0
    bh8 vA[8], vB[8];
    #pragma unroll
    for (int kk = 0; kk < 4; ++kk) {
        vA[kk]     = *(const bh8*)(vr0 + kk * 16);
        vA[4 + kk] = *(const bh8*)(vr1 + kk * 16);
    }
    bh8 kf = *(const bh8*)kptr;

    for (int jt = 0; jt < 64; ++jt) {
        char* Pc = lds + (jt & 1) * 8192;
        // ---- QK: 4x 16x16x32 (A=K rows j, B=Q cols i), exp, pack, P->LDS[cur]
        f32x4 sa[4];
        #pragma unroll
        for (int is4 = 0; is4 < 4; ++is4)
            sa[is4] = __builtin_amdgcn_mfma_f32_16x16x32_bf16(kf, qf[is4], initc, 0, 0, 0);
        kf = *(const bh8*)(kptr + (size_t)((jt + 1) & 63) * 2048);  // prefetch
        int jg = w * 2 + (quad >> 1);
        #pragma unroll
        for (int is4 = 0; is4 < 4; ++is4) {
            float p[4];
            #pragma unroll
            for (int r = 0; r < 4; ++r) { p[r] = __expf(sa[is4][r]); lsum[is4] += p[r]; }
            int i_ = is4 * 16 + c15;
            *(int2*)(Pc + i_ * 128 + ((jg ^ (c15 & 7)) * 16) + (quad & 1) * 8) =
                make_int2(pack2bf(p[0], p[1]), pack2bf(p[2], p[3]));
        }
        __syncthreads();   // publish P[cur] (no DMA in flight -> cheap drain)

        // ---- V register prefetch for next step (consumed after next barrier)
        if (jt < 63) {
            const short* v0n = vr0 + (size_t)(jt + 1) * 64;
            const short* v1n = vr1 + (size_t)(jt + 1) * 64;
            #pragma unroll
            for (int kk = 0; kk < 4; ++kk) {
                vB[kk]     = *(const bh8*)(v0n + kk * 16);
                vB[4 + kk] = *(const bh8*)(v1n + kk * 16);
            }
        }

        // ---- P fragments (32x32 B-operand): n=i=l31, k=j=kk*16+l5*8+e
        bh8 pf[2][4];
        #pragma unroll
        for (int is = 0; is < 2; ++is)
            #pragma unroll
            for (int kk = 0; kk < 4; ++kk) {
                int irow = is * 32 + l31;
                int slot = (kk * 2 + l5) ^ (irow & 7);
                pf[is][kk] = *(const bh8*)(Pc + irow * 128 + slot * 16);
            }
        // ---- PV: 16x mfma_32x32x16, 4 independent acc chains
        #pragma unroll
        for (int kk = 0; kk < 4; ++kk) {
            acc[0][0] = __builtin_amdgcn_mfma_f32_32x32x16_bf16(vA[kk],     pf[0][kk], acc[0][0], 0, 0, 0);
            acc[0][1] = __builtin_amdgcn_mfma_f32_32x32x16_bf16(vA[kk],     pf[1][kk], acc[0][1], 0, 0, 0);
            acc[1][0] = __builtin_amdgcn_mfma_f32_32x32x16_bf16(vA[4 + kk], pf[0][kk], acc[1][0], 0, 0, 0);
            acc[1][1] = __builtin_amdgcn_mfma_f32_32x32x16_bf16(vA[4 + kk], pf[1][kk], acc[1][1], 0, 0, 0);
        }
        #pragma unroll
        for (int q2 = 0; q2 < 8; ++q2) vA[q2] = vB[q2];
    }

    // ---- softmax denominators: quad-reduce then cross-wave via LDS
    #pragma unroll
    for (int is4 = 0; is4 < 4; ++is4) {
        lsum[is4] += __shfl_xor(lsum[is4], 16);
        lsum[is4] += __shfl_xor(lsum[is4], 32);
    }
    float* lred = (float*)(lds + 16384);
    __syncthreads();
    if (lane < 16) {
        #pragma unroll
        for (int is4 = 0; is4 < 4; ++is4) lred[w * 64 + is4 * 16 + lane] = lsum[is4];
    }
    __syncthreads();

    float gm = gamma[0];
    const float* xb2 = x + (size_t)b * CC * NN;
    float* ob = out + (size_t)b * CC * NN;
    #pragma unroll
    for (int is = 0; is < 2; ++is) {
        int i_l = is * 32 + l31;
        float lt = lred[i_l] + lred[64 + i_l] + lred[128 + i_l] + lred[192 + i_l];
        float linv = 1.0f / lt;
        int i = i0 + i_l;
        #pragma unroll
        for (int cs = 0; cs < 2; ++cs) {
            #pragma unroll
            for (int r = 0; r < 16; ++r) {
                int c = w * 64 + cs * 32 + (r & 3) + 8 * (r >> 2) + 4 * l5;
                ob[(size_t)c * NN + i] = gm * acc[cs][is][r] * linv + xb2[(size_t)c * NN + i];
            }
        }
    }
}

extern "C" void kernel_launch(void* const* d_in, const int* in_sizes, int n_in,
                              void* d_out, int out_size, void* d_ws, size_t ws_size,
                              hipStream_t stream) {
    const float* x     = (const float*)d_in[0];
    const float* Wq    = (const float*)d_in[1];
    const float* bq    = (const float*)d_in[2];
    const float* Wk    = (const float*)d_in[3];
    const float* bk    = (const float*)d_in[4];
    const float* Wv    = (const float*)d_in[5];
    const float* bv    = (const float*)d_in[6];
    const float* gamma = (const float*)d_in[7];
    float* out = (float*)d_out;
    char*  ws  = (char*)d_ws;
    short* Wpk  = (short*)(ws + WPK_OFF);
    float* ball = (float*)(ws + BALL_OFF);
    short* qbf  = (short*)(ws + QBF_OFF);
    short* kbf  = (short*)(ws + KBF_OFF);
    short* vbf  = (short*)(ws + VBF_OFF);

    prep_w<<<40, 256, 0, stream>>>(Wq, bq, Wk, bk, Wv, bv, Wpk, ball);
    proj<<<512, 256, 0, stream>>>(x, Wpk, ball, qbf, kbf, vbf);
    flash_attn<<<256, 256, 0, stream>>>(qbf, kbf, vbf, x, gamma, out);
}

// Round 9
// 152.132 us; speedup vs baseline: 1.3322x; 1.3322x over previous
//
#include <hip/hip_runtime.h>

#define BB 4
#define CC 256
#define NN 4096

typedef __attribute__((ext_vector_type(8))) short bh8;
typedef __attribute__((ext_vector_type(4))) float f32x4;

// workspace layout (bytes)
#define WPK_OFF  0                        // 20*8*64*8 bf16 = 163840 (B-frag packed W)
#define BALL_OFF 163840                   // 320 f32
#define QBF_OFF  165888                   // B*N*32 bf16 = 1 MB
#define KBF_OFF  (165888 + 1048576)
#define VBF_OFF  (165888 + 2097152)       // B*C*N bf16 = 8 MB

typedef const __attribute__((address_space(1))) void* gas_t;
typedef __attribute__((address_space(3))) void* las_t;
__device__ inline void gld16(const void* g, void* l) {
    __builtin_amdgcn_global_load_lds((gas_t)g, (las_t)l, 16, 0, 0);
}

__device__ inline int pack2bf(float a, float b) {
    unsigned ua = __builtin_bit_cast(unsigned, a) + 0x8000u;
    unsigned ub = __builtin_bit_cast(unsigned, b) + 0x8000u;
    return (int)__builtin_amdgcn_perm(ub, ua, 0x07060302u);
}
__device__ inline short f2bf1(float a) {
    return (short)((__builtin_bit_cast(unsigned, a) + 0x8000u) >> 16);
}

// ---------------- prep: Wpk B-fragments + ball
__global__ __launch_bounds__(256) void prep_w(const float* __restrict__ Wq,
        const float* __restrict__ bq, const float* __restrict__ Wk,
        const float* __restrict__ bk, const float* __restrict__ Wv,
        const float* __restrict__ bv, short* __restrict__ Wpk,
        float* __restrict__ ball) {
    int tid = blockIdx.x * 256 + threadIdx.x;
    if (tid < 10240) {
        int lane = tid & 63;
        int fc = tid >> 6;                 // mt*8 + ck
        int mt = fc >> 3, ck = fc & 7;
        int m = mt * 16 + (lane & 15);
        int c0 = ck * 32 + (lane >> 4) * 8;
        const float* wrow;
        if (m < 32)      wrow = Wq + m * 256;
        else if (m < 64) wrow = Wk + (m - 32) * 256;
        else             wrow = Wv + (m - 64) * 256;
        int d[4];
        #pragma unroll
        for (int p = 0; p < 4; ++p)
            d[p] = pack2bf(wrow[c0 + 2 * p], wrow[c0 + 2 * p + 1]);
        *(int4*)(Wpk + tid * 8) = make_int4(d[0], d[1], d[2], d[3]);
    }
    if (tid < 320) {
        float b2 = tid < 32 ? bq[tid] : (tid < 64 ? bk[tid - 32] : bv[tid - 64]);
        ball[tid] = b2;
    }
}

// ---------------- projections as MFMA GEMM, x staged coalesced via LDS (R8 design)
__global__ __launch_bounds__(256) void proj(const float* __restrict__ x,
        const short* __restrict__ Wpk, const float* __restrict__ ball,
        short* __restrict__ qbf, short* __restrict__ kbf,
        short* __restrict__ vbf) {
    __shared__ float xs[8192];             // 32 KB: x[256c][32n] fp32, granule-linear
    int t = threadIdx.x;
    int w = t >> 6, lane = t & 63, quad = lane >> 4, c15 = lane & 15;
    int b = blockIdx.x >> 7;
    int n0 = (blockIdx.x & 127) * 32;
    const float* xb = x + (size_t)b * CC * NN + n0;

    #pragma unroll
    for (int r = 0; r < 8; ++r) {
        const float* src = xb + (size_t)(w * 64 + r * 8 + (lane >> 3)) * NN + (lane & 7) * 4;
        gld16(src, (char*)xs + w * 8192 + r * 1024);
    }
    __syncthreads();

    int ns = w & 1, mh = w >> 1;           // n-sub, m-half
    int nb = ns * 16;

    bh8 af[8];
    #pragma unroll
    for (int ck = 0; ck < 8; ++ck) {
        float v[8];
        #pragma unroll
        for (int e = 0; e < 8; ++e)
            v[e] = xs[(ck * 32 + quad * 8 + e) * 32 + nb + c15];
        int d[4];
        #pragma unroll
        for (int p = 0; p < 4; ++p) d[p] = pack2bf(v[2 * p], v[2 * p + 1]);
        af[ck] = __builtin_bit_cast(bh8, make_int4(d[0], d[1], d[2], d[3]));
    }

    #pragma unroll
    for (int mpi = 0; mpi < 5; ++mpi) {
        int mtA = mh * 10 + mpi * 2, mtB = mtA + 1;
        float blA = ball[mtA * 16 + c15], blB = ball[mtB * 16 + c15];
        f32x4 accA = {blA, blA, blA, blA}, accB = {blB, blB, blB, blB};
        #pragma unroll
        for (int ck = 0; ck < 8; ++ck) {
            bh8 wfA = *(const bh8*)(Wpk + ((mtA * 8 + ck) * 64 + lane) * 8);
            bh8 wfB = *(const bh8*)(Wpk + ((mtB * 8 + ck) * 64 + lane) * 8);
            accA = __builtin_amdgcn_mfma_f32_16x16x32_bf16(af[ck], wfA, accA, 0, 0, 0);
            accB = __builtin_amdgcn_mfma_f32_16x16x32_bf16(af[ck], wfB, accB, 0, 0, 0);
        }
        #pragma unroll
        for (int half = 0; half < 2; ++half) {
            int mt = mtA + half;
            f32x4 acc = half ? accB : accA;
            if (mt < 4) {
                short* dst = (mt < 2) ? qbf : kbf;
                int m = (mt & 1) * 16 + c15;
                #pragma unroll
                for (int r = 0; r < 4; ++r)
                    dst[(size_t)(b * NN + n0 + nb + quad * 4 + r) * 32 + m] = f2bf1(acc[r]);
            } else {
                int c = mt * 16 + c15 - 64;
                int2 pk;
                pk.x = pack2bf(acc[0], acc[1]);
                pk.y = pack2bf(acc[2], acc[3]);
                *(int2*)(vbf + (size_t)b * CC * NN + (size_t)c * NN + n0 + nb + quad * 4) = pk;
            }
        }
    }
}

// ---------------- fused flash attention v4: split-c, 2 blocks/CU
// block = 128c x 64i x all-j, 4 waves. grid 512 = 64 i-tiles x 2 c-halves x 4 b.
// QK role: jsub = w (16 j/step), all 64 i. PV role: mg=w&1 (64c), nh=w>>1 (32i).
// Single barrier/step: P dbuf + V dbuf; V-DMA issued AFTER the barrier.
__global__ __launch_bounds__(256, 2) void flash_attn(
        const short* __restrict__ qbf, const short* __restrict__ kbf,
        const short* __restrict__ vbf, const float* __restrict__ x,
        const float* __restrict__ gamma, float* __restrict__ out) {
    __shared__ char lds[50176];  // V 2x16KB @0 | P 2x8KB @32768 | lred 1KB @49152

    int bid = blockIdx.x;
    int b = bid & 3;                        // batch -> XCD pair (K/V L2-resident)
    int ch = (bid >> 2) & 1;                // c-half: rows [ch*128, ch*128+128)
    int i0 = (bid >> 3) * 64;
    int t = threadIdx.x;
    int w = t >> 6, lane = t & 63, quad = lane >> 4, c15 = lane & 15;
    int mg = w & 1, nh = w >> 1;

    const short* qb = qbf + (size_t)b * NN * 32;
    const short* kb = kbf + (size_t)b * NN * 32;
    const short* vb = vbf + (size_t)b * CC * NN;

    // Q fragments (B-operand) for 4 i-subtiles (QK role needs all 64 i)
    bh8 qf[4];
    #pragma unroll
    for (int is4 = 0; is4 < 4; ++is4)
        qf[is4] = *(const bh8*)(qb + (size_t)(i0 + is4 * 16 + c15) * 32 + quad * 8);

    // K pointer for this wave's j-subtile (A-frags from global/L2)
    const short* kptr = kb + (size_t)(w * 16 + c15) * 32 + quad * 8;

    // V staging: wave w stages local rows [w*32, w*32+32): 4 gld16/step.
    // lane l covers row w*32 + r*8 + (l>>3), granule (l&7)^((l>>3)&7) (XOR swz);
    // LDS dst is WAVE-UNIFORM (HW: lane l -> base + l*16).
    const short* vsg = vb + (size_t)(ch * 128 + w * 32 + (lane >> 3)) * NN
                          + ((lane & 7) ^ ((lane >> 3) & 7)) * 8;
    char* vdst = lds + w * 4096;            // uniform per wave

    char* Pt = lds + 32768;
    float* lred = (float*)(lds + 49152);

    f32x4 acc[4][2];
    #pragma unroll
    for (int ms = 0; ms < 4; ++ms) {
        acc[ms][0] = (f32x4){0.f, 0.f, 0.f, 0.f};
        acc[ms][1] = (f32x4){0.f, 0.f, 0.f, 0.f};
    }
    float lsum[4] = {0.f, 0.f, 0.f, 0.f};
    const f32x4 initc = {-12.f, -12.f, -12.f, -12.f};  // softmax shift folded into C

    // prologue: stage V buf0, load K frag for step 0
    #pragma unroll
    for (int r = 0; r < 4; ++r) gld16(vsg + r * 8 * NN, vdst + r * 1024);
    bh8 kf = *(const bh8*)kptr;
    __syncthreads();   // drains vmcnt -> buf0 staged

    for (int jt = 0; jt < 64; ++jt) {
        int cur = jt & 1;
        // ---- QK: 4x 16x16 S^T tiles (A=K j-rows, B=Q i-cols)
        f32x4 sa[4];
        #pragma unroll
        for (int is4 = 0; is4 < 4; ++is4)
            sa[is4] = __builtin_amdgcn_mfma_f32_16x16x32_bf16(kf, qf[is4], initc, 0, 0, 0);
        kf = *(const bh8*)(kptr + (size_t)((jt + 1) & 63) * 2048);  // prefetch
        // exp + pack + P->LDS[cur]
        char* Pc = Pt + cur * 8192;
        int jg = w * 2 + (quad >> 1);
        #pragma unroll
        for (int is4 = 0; is4 < 4; ++is4) {
            float p[4];
            #pragma unroll
            for (int r = 0; r < 4; ++r) { p[r] = __expf(sa[is4][r]); lsum[is4] += p[r]; }
            int i_ = is4 * 16 + c15;
            *(int2*)(Pc + i_ * 128 + ((jg ^ (c15 & 7)) * 16) + (quad & 1) * 8) =
                make_int2(pack2bf(p[0], p[1]), pack2bf(p[2], p[3]));
        }

        // single barrier: publishes P[cur]; implicit vmcnt(0) drains the V-DMA
        // issued after the PREVIOUS barrier (one full step of slack)
        __syncthreads();

        // ---- issue next V staging AFTER the barrier (safety by barrier order)
        if (jt < 63) {
            const short* vs = vsg + (jt + 1) * 64;
            char* vd = vdst + ((cur ^ 1) << 14);   // uniform per wave
            #pragma unroll
            for (int r = 0; r < 4; ++r) gld16(vs + r * 8 * NN, vd + r * 1024);
        }

        // ---- PV: O^T(64c x 32i) += V(A) . P(B) from V[cur], P[cur]
        const char* Vb = lds + cur * 16384;
        #pragma unroll
        for (int kk = 0; kk < 2; ++kk) {
            int gs = (kk * 4 + quad);
            bh8 pfa = *(const bh8*)(Pc + (nh * 32 + c15) * 128 + ((gs ^ (c15 & 7)) * 16));
            bh8 pfb = *(const bh8*)(Pc + (nh * 32 + 16 + c15) * 128 + ((gs ^ (c15 & 7)) * 16));
            #pragma unroll
            for (int ms = 0; ms < 4; ++ms) {
                int cl = mg * 64 + ms * 16 + c15;    // local V row 0..127
                bh8 vf = *(const bh8*)(Vb + cl * 128 + ((gs ^ (c15 & 7)) * 16));
                acc[ms][0] = __builtin_amdgcn_mfma_f32_16x16x32_bf16(vf, pfa, acc[ms][0], 0, 0, 0);
                acc[ms][1] = __builtin_amdgcn_mfma_f32_16x16x32_bf16(vf, pfb, acc[ms][1], 0, 0, 0);
            }
        }
    }

    // ---- softmax denominators: quad-reduce, then cross-wave (4 jsubs) via LDS
    #pragma unroll
    for (int is4 = 0; is4 < 4; ++is4) {
        lsum[is4] += __shfl_xor(lsum[is4], 16);
        lsum[is4] += __shfl_xor(lsum[is4], 32);
    }
    __syncthreads();   // last PV reads done (lred region is separate but keep order)
    if (lane < 16) {
        #pragma unroll
        for (int is4 = 0; is4 < 4; ++is4) lred[w * 64 + is4 * 16 + lane] = lsum[is4];
    }
    __syncthreads();

    float gm = gamma[0];
    const float* xb2 = x + (size_t)b * CC * NN;
    float* ob = out + (size_t)b * CC * NN;
    #pragma unroll
    for (int is = 0; is < 2; ++is) {
        int il = nh * 32 + is * 16 + c15;
        float lt = lred[il] + lred[64 + il] + lred[128 + il] + lred[192 + il];
        float linv = 1.0f / lt;
        int i = i0 + il;
        #pragma unroll
        for (int ms = 0; ms < 4; ++ms) {
            #pragma unroll
            for (int r = 0; r < 4; ++r) {
                int c = ch * 128 + mg * 64 + ms * 16 + quad * 4 + r;
                ob[(size_t)c * NN + i] = gm * acc[ms][is][r] * linv + xb2[(size_t)c * NN + i];
            }
        }
    }
}

extern "C" void kernel_launch(void* const* d_in, const int* in_sizes, int n_in,
                              void* d_out, int out_size, void* d_ws, size_t ws_size,
                              hipStream_t stream) {
    const float* x     = (const float*)d_in[0];
    const float* Wq    = (const float*)d_in[1];
    const float* bq    = (const float*)d_in[2];
    const float* Wk    = (const float*)d_in[3];
    const float* bk    = (const float*)d_in[4];
    const float* Wv    = (const float*)d_in[5];
    const float* bv    = (const float*)d_in[6];
    const float* gamma = (const float*)d_in[7];
    float* out = (float*)d_out;
    char*  ws  = (char*)d_ws;
    short* Wpk  = (short*)(ws + WPK_OFF);
    float* ball = (float*)(ws + BALL_OFF);
    short* qbf  = (short*)(ws + QBF_OFF);
    short* kbf  = (short*)(ws + KBF_OFF);
    short* vbf  = (short*)(ws + VBF_OFF);

    prep_w<<<40, 256, 0, stream>>>(Wq, bq, Wk, bk, Wv, bv, Wpk, ball);
    proj<<<512, 256, 0, stream>>>(x, Wpk, ball, qbf, kbf, vbf);
    flash_attn<<<512, 256, 0, stream>>>(qbf, kbf, vbf, x, gamma, out);
}